// Round 1
// baseline (4359.011 us; speedup 1.0000x reference)
//
#include <hip/hip_runtime.h>
#include <math.h>

#define T_DIM 512
#define B_DIM 256
#define D_DIM 256
#define H_DIM 256
#define G_DIM 1024   // 4*H
#define K_DIM 512    // D + H
#define NROUNDS 40
#define TILE_ROWS 16

__device__ __forceinline__ unsigned int f2bf(float f) {
    unsigned int b = __float_as_uint(f);
    return (b + 0x7FFFu + ((b >> 16) & 1u)) >> 16;   // round-to-nearest-even bf16
}

// Build packed-bf16 transposed weights: Wp[kp][g] holds bf16(W[2kp][g]) | bf16(W[2kp+1][g])<<16
// where W[k][g] = (k<D) ? W_ih[g][k] : W_hh[g][k-D].  Also bias[g] = b_ih[g]+b_hh[g].
__global__ __launch_bounds__(256) void k_prep_weights(
    const float* __restrict__ W_ih, const float* __restrict__ W_hh,
    const float* __restrict__ b_ih, const float* __restrict__ b_hh,
    unsigned int* __restrict__ Wp, float* __restrict__ bias)
{
    const int idx = blockIdx.x * 256 + threadIdx.x;   // 0 .. (K/2)*G-1
    const int kp = idx >> 10, g = idx & (G_DIM - 1);
    const int k0 = 2 * kp, k1 = 2 * kp + 1;
    const float we = (k0 < D_DIM) ? W_ih[g * D_DIM + k0] : W_hh[g * H_DIM + (k0 - D_DIM)];
    const float wo = (k1 < D_DIM) ? W_ih[g * D_DIM + k1] : W_hh[g * H_DIM + (k1 - D_DIM)];
    Wp[idx] = (f2bf(wo) << 16) | f2bf(we);
    if (idx < G_DIM) bias[idx] = b_ih[idx] + b_hh[idx];
}

// Per-batch scan over t: k(t,b) = steps since last reset. One block, thread = batch col.
__global__ __launch_bounds__(256) void k_prep_kmap(
    const int* __restrict__ done, int* __restrict__ kmap,
    int* __restrict__ counts, int* __restrict__ offs, int* __restrict__ cursor)
{
    __shared__ int lcnt[NROUNDS];
    const int tid = threadIdx.x;
    if (tid < NROUNDS) { lcnt[tid] = 0; cursor[tid] = 0; }
    __syncthreads();
    int kv = 0;
    for (int t = 0; t < T_DIM; ++t) {
        const int p = t * B_DIM + tid;
        kv = done[p] ? 0 : (t == 0 ? 0 : kv + 1);
        if (kv > NROUNDS - 1) kv = NROUNDS - 1;   // safety clamp (validation would catch)
        kmap[p] = kv;
        atomicAdd(&lcnt[kv], 1);
    }
    __syncthreads();
    if (tid == 0) {
        int s = 0;
        for (int i = 0; i < NROUNDS; ++i) { counts[i] = lcnt[i]; offs[i] = s; s += lcnt[i]; }
    }
}

// Scatter positions into round-ordered row lists. Order within a round is
// irrelevant: each row's output is a pure function of its own inputs.
__global__ __launch_bounds__(256) void k_scatter(
    const int* __restrict__ kmap, const int* __restrict__ offs,
    int* __restrict__ cursor, int* __restrict__ rowlist)
{
    const int pos = blockIdx.x * 256 + threadIdx.x;
    const int kv = kmap[pos];
    const int idx = atomicAdd(&cursor[kv], 1);
    rowlist[offs[kv] + idx] = pos;
}

// Round k: batched [nk x 512] x [512 x 1024] + LSTM pointwise.
// Thread owns hidden unit u = tid: gates u, 256+u, 512+u, 768+u  -> no gate exchange needed.
__global__ __launch_bounds__(256) void k_round(
    const float* __restrict__ x, const float* __restrict__ h0,
    const float* __restrict__ c0, const int* __restrict__ done,
    const unsigned int* __restrict__ Wp, const float* __restrict__ bias,
    const int* __restrict__ counts, const int* __restrict__ offs,
    const int* __restrict__ rowlist,
    float* __restrict__ out, float* __restrict__ c_buf, int k)
{
    __shared__ float A[TILE_ROWS][K_DIM];   // 32 KB
    __shared__ int posr[TILE_ROWS];
    const int nk = counts[k];
    const int base = offs[k];
    const int tid = threadIdx.x;

    for (int tile = blockIdx.x; tile * TILE_ROWS < nk; tile += gridDim.x) {
        const int row0 = tile * TILE_ROWS;
        const int nrows = min(TILE_ROWS, nk - row0);
        if (tid < TILE_ROWS)
            posr[tid] = (tid < nrows) ? rowlist[base + row0 + tid] : -1;
        __syncthreads();

        // Stage A rows: [x_t | h_{t-1} (masked)] ; f32
        for (int idx = tid; idx < TILE_ROWS * K_DIM; idx += 256) {
            const int r = idx >> 9, c = idx & (K_DIM - 1);
            const int pos = posr[r];
            float v = 0.0f;
            if (pos >= 0) {
                if (c < D_DIM) {
                    v = x[pos * D_DIM + c];                       // x[t][b][c]
                } else {
                    const int u = c - D_DIM;
                    if (k > 0)          v = out[(pos - B_DIM) * H_DIM + u];   // h at t-1
                    else if (!done[pos]) v = h0[(pos & (B_DIM - 1)) * H_DIM + u]; // t==0 start
                    // done==1 -> reset to 0
                }
            }
            A[r][c] = v;
        }
        __syncthreads();

        float acc0[TILE_ROWS], acc1[TILE_ROWS], acc2[TILE_ROWS], acc3[TILE_ROWS];
        #pragma unroll
        for (int r = 0; r < TILE_ROWS; ++r) { acc0[r]=0.f; acc1[r]=0.f; acc2[r]=0.f; acc3[r]=0.f; }

        for (int kp = 0; kp < K_DIM / 2; ++kp) {
            const unsigned int u0 = Wp[kp * G_DIM + tid];
            const unsigned int u1 = Wp[kp * G_DIM + 256 + tid];
            const unsigned int u2 = Wp[kp * G_DIM + 512 + tid];
            const unsigned int u3 = Wp[kp * G_DIM + 768 + tid];
            const float w0e = __uint_as_float(u0 << 16), w0o = __uint_as_float(u0 & 0xFFFF0000u);
            const float w1e = __uint_as_float(u1 << 16), w1o = __uint_as_float(u1 & 0xFFFF0000u);
            const float w2e = __uint_as_float(u2 << 16), w2o = __uint_as_float(u2 & 0xFFFF0000u);
            const float w3e = __uint_as_float(u3 << 16), w3o = __uint_as_float(u3 & 0xFFFF0000u);
            #pragma unroll
            for (int r = 0; r < TILE_ROWS; ++r) {
                const float2 av = *reinterpret_cast<const float2*>(&A[r][2 * kp]); // LDS broadcast
                acc0[r] = fmaf(av.y, w0o, fmaf(av.x, w0e, acc0[r]));
                acc1[r] = fmaf(av.y, w1o, fmaf(av.x, w1e, acc1[r]));
                acc2[r] = fmaf(av.y, w2o, fmaf(av.x, w2e, acc2[r]));
                acc3[r] = fmaf(av.y, w3o, fmaf(av.x, w3e, acc3[r]));
            }
        }

        const float bi = bias[tid], bf = bias[256 + tid], bg = bias[512 + tid], bo = bias[768 + tid];
        for (int r = 0; r < nrows; ++r) {
            const int pos = posr[r];
            float cp = 0.0f;
            if (k > 0)           cp = c_buf[(pos - B_DIM) * H_DIM + tid];
            else if (!done[pos]) cp = c0[(pos & (B_DIM - 1)) * H_DIM + tid];
            const float gi = 1.0f / (1.0f + expf(-(acc0[r] + bi)));
            const float gf = 1.0f / (1.0f + expf(-(acc1[r] + bf)));
            const float gg = tanhf(acc2[r] + bg);
            const float go = 1.0f / (1.0f + expf(-(acc3[r] + bo)));
            const float cn = gf * cp + gi * gg;
            const float hn = go * tanhf(cn);
            c_buf[pos * H_DIM + tid] = cn;
            out[pos * H_DIM + tid]  = hn;       // h IS the output feature
        }
        __syncthreads();   // protect A/posr before next tile
    }
}

// hT = out rows at t=511 ; cT = c_buf at t=511
__global__ __launch_bounds__(256) void k_final(const float* __restrict__ c_buf, float* __restrict__ out)
{
    const size_t i = (size_t)blockIdx.x * 256 + threadIdx.x;   // 0..65535
    const size_t featN = (size_t)T_DIM * B_DIM * H_DIM;
    const size_t last  = (size_t)(T_DIM - 1) * B_DIM * H_DIM;
    out[featN + i] = out[last + i];
    out[featN + (size_t)B_DIM * H_DIM + i] = c_buf[last + i];
}

extern "C" void kernel_launch(void* const* d_in, const int* in_sizes, int n_in,
                              void* d_out, int out_size, void* d_ws, size_t ws_size,
                              hipStream_t stream)
{
    const float* x    = (const float*)d_in[0];
    const float* h0   = (const float*)d_in[1];
    const float* c0   = (const float*)d_in[2];
    const float* W_ih = (const float*)d_in[3];
    const float* W_hh = (const float*)d_in[4];
    const float* b_ih = (const float*)d_in[5];
    const float* b_hh = (const float*)d_in[6];
    const int*   done = (const int*)d_in[7];
    float* out = (float*)d_out;

    char* ws = (char*)d_ws;
    size_t off = 0;
    float* c_buf = (float*)(ws + off);        off += (size_t)T_DIM * B_DIM * H_DIM * 4;   // 128 MiB
    unsigned int* Wp = (unsigned int*)(ws + off); off += (size_t)(K_DIM / 2) * G_DIM * 4; // 1 MiB
    float* bias = (float*)(ws + off);         off += (size_t)G_DIM * 4;
    int* kmap    = (int*)(ws + off);          off += (size_t)T_DIM * B_DIM * 4;           // 512 KiB
    int* rowlist = (int*)(ws + off);          off += (size_t)T_DIM * B_DIM * 4;           // 512 KiB
    int* counts  = (int*)(ws + off);          off += 256;
    int* offs    = (int*)(ws + off);          off += 256;
    int* cursor  = (int*)(ws + off);          off += 256;
    // total ~136.3 MB of workspace

    k_prep_weights<<<(K_DIM / 2) * G_DIM / 256, 256, 0, stream>>>(W_ih, W_hh, b_ih, b_hh, Wp, bias);
    k_prep_kmap<<<1, 256, 0, stream>>>(done, kmap, counts, offs, cursor);
    k_scatter<<<T_DIM * B_DIM / 256, 256, 0, stream>>>(kmap, offs, cursor, rowlist);

    int est = 70000;   // upper bound on N_0; halves each round (done ~ Bernoulli(0.5))
    for (int k = 0; k < NROUNDS; ++k) {
        int tiles = est / TILE_ROWS + 32;
        if (tiles > 4352) tiles = 4352;
        k_round<<<tiles, 256, 0, stream>>>(x, h0, c0, done, Wp, bias, counts, offs, rowlist, out, c_buf, k);
        est >>= 1;
    }
    k_final<<<B_DIM * H_DIM / 256, 256, 0, stream>>>(c_buf, out);
}

// Round 2
// 2288.725 us; speedup vs baseline: 1.9046x; 1.9046x over previous
//
#include <hip/hip_runtime.h>
#include <math.h>

#define T_DIM 512
#define B_DIM 256
#define D_DIM 256
#define H_DIM 256
#define G_DIM 1024   // 4*H
#define K_DIM 512    // D + H
#define NROUNDS 40
#define TILE_ROWS 32

typedef __attribute__((ext_vector_type(8))) short short8;
typedef __attribute__((ext_vector_type(4))) float f32x4;

__device__ __forceinline__ unsigned int f2bf(float f) {
    unsigned int b = __float_as_uint(f);
    return (b + 0x7FFFu + ((b >> 16) & 1u)) >> 16;   // round-to-nearest-even bf16
}
__device__ __forceinline__ float sigm(float x) { return 1.0f / (1.0f + __expf(-x)); }
__device__ __forceinline__ float tanh_fast(float x) { return 2.0f / (1.0f + __expf(-2.0f * x)) - 1.0f; }

// Prepack W into MFMA B-fragment order, bf16.
// Wb u32 slot idx: jp = idx&3, l = (idx>>2)&63, ks = (idx>>8)&15, nt = idx>>12
//   g = nt*16 + (l&15); k = ks*32 + ((l>>4)<<3) + 2*jp (+0,1)
//   W[k][g] = k<D ? W_ih[g][k] : W_hh[g][k-D]
__global__ __launch_bounds__(256) void k_prep_weights(
    const float* __restrict__ W_ih, const float* __restrict__ W_hh,
    const float* __restrict__ b_ih, const float* __restrict__ b_hh,
    unsigned int* __restrict__ Wb, float* __restrict__ bias)
{
    const int idx = blockIdx.x * 256 + threadIdx.x;   // 0 .. 262143
    const int jp = idx & 3, l = (idx >> 2) & 63, ks = (idx >> 8) & 15, nt = idx >> 12;
    const int g = nt * 16 + (l & 15);
    const int k0 = ks * 32 + ((l >> 4) << 3) + 2 * jp;   // even; k0,k0+1 same side of D boundary
    const float w0 = (k0 < D_DIM) ? W_ih[g * D_DIM + k0] : W_hh[g * H_DIM + (k0 - D_DIM)];
    const float w1 = (k0 + 1 < D_DIM) ? W_ih[g * D_DIM + k0 + 1] : W_hh[g * H_DIM + (k0 + 1 - D_DIM)];
    Wb[idx] = (f2bf(w1) << 16) | f2bf(w0);
    if (idx < G_DIM) bias[idx] = b_ih[idx] + b_hh[idx];
}

// Per-batch scan over t: k(t,b) = steps since last reset.
__global__ __launch_bounds__(256) void k_prep_kmap(
    const int* __restrict__ done, int* __restrict__ kmap,
    int* __restrict__ counts, int* __restrict__ offs, int* __restrict__ cursor)
{
    __shared__ int lcnt[NROUNDS];
    const int tid = threadIdx.x;
    if (tid < NROUNDS) { lcnt[tid] = 0; cursor[tid] = 0; }
    __syncthreads();
    int kv = 0;
    for (int t = 0; t < T_DIM; ++t) {
        const int p = t * B_DIM + tid;
        kv = done[p] ? 0 : (t == 0 ? 0 : kv + 1);
        if (kv > NROUNDS - 1) kv = NROUNDS - 1;
        kmap[p] = kv;
        atomicAdd(&lcnt[kv], 1);
    }
    __syncthreads();
    if (tid == 0) {
        int s = 0;
        for (int i = 0; i < NROUNDS; ++i) { counts[i] = lcnt[i]; offs[i] = s; s += lcnt[i]; }
    }
}

__global__ __launch_bounds__(256) void k_scatter(
    const int* __restrict__ kmap, const int* __restrict__ offs,
    int* __restrict__ cursor, int* __restrict__ rowlist)
{
    const int pos = blockIdx.x * 256 + threadIdx.x;
    const int kv = kmap[pos];
    const int idx = atomicAdd(&cursor[kv], 1);
    rowlist[offs[kv] + idx] = pos;
}

// Round k: [nk x 512] x [512 x 1024] bf16 MFMA + fused LSTM pointwise.
// Block: 256 thr (4 waves). Wave w owns hidden units u in [w*64, w*64+64) -- all 4 gates.
// A staged in LDS in fragment order: slot ((ks*2+mb)*64 + l)*8 + j  <->
//   row = mb*16 + (l&15), k = ks*32 + ((l>>4)<<3) + j
__global__ __launch_bounds__(256, 2) void k_round(
    const float* __restrict__ x, const float* __restrict__ h0,
    const float* __restrict__ c0, const int* __restrict__ done,
    const short* __restrict__ Wb, const float* __restrict__ bias,
    const int* __restrict__ counts, const int* __restrict__ offs,
    const int* __restrict__ rowlist,
    float* __restrict__ out, float* __restrict__ c_buf, int kk)
{
    __shared__ short A_lds[16 * 2 * 64 * 8];   // 32 KiB
    const int nk = counts[kk];
    const int base = offs[kk];
    const int tid = threadIdx.x;
    const int w = tid >> 6, l = tid & 63;
    const int lr = l >> 4, lc = l & 15;

    for (int tile = blockIdx.x; tile * TILE_ROWS < nk; tile += gridDim.x) {
        const int row0 = tile * TILE_ROWS;

        // ---- stage A tile (f32 -> bf16, fragment order, conflict-free) ----
        unsigned int* A_u32 = (unsigned int*)A_lds;
        for (int it = 0; it < 32; ++it) {
            const int s = it * 256 + tid;             // 0..8191 u32 slots
            const int ks = s >> 9, mb = (s >> 8) & 1, sl = (s >> 2) & 63, jp = s & 3;
            const int r = mb * 16 + (sl & 15);
            const int c = ks * 32 + ((sl >> 4) << 3) + 2 * jp;
            const int gr = row0 + r;
            float v0 = 0.0f, v1 = 0.0f;
            if (gr < nk) {
                const int pos = rowlist[base + gr];
                if (c < D_DIM) {
                    v0 = x[(size_t)pos * D_DIM + c];
                    v1 = x[(size_t)pos * D_DIM + c + 1];
                } else {
                    const int u = c - D_DIM;
                    if (kk > 0) {
                        const float* hp = out + (size_t)(pos - B_DIM) * H_DIM + u;
                        v0 = hp[0]; v1 = hp[1];
                    } else if (!done[pos]) {
                        const float* hp = h0 + (size_t)(pos & (B_DIM - 1)) * H_DIM + u;
                        v0 = hp[0]; v1 = hp[1];
                    }
                }
            }
            A_u32[s] = (f2bf(v1) << 16) | f2bf(v0);
        }
        __syncthreads();

        // ---- MFMA: acc[gt][mb][uq] ----
        f32x4 acc[4][2][4];
        #pragma unroll
        for (int gt = 0; gt < 4; ++gt)
            #pragma unroll
            for (int mb = 0; mb < 2; ++mb)
                #pragma unroll
                for (int uq = 0; uq < 4; ++uq)
                    acc[gt][mb][uq] = (f32x4){0.f, 0.f, 0.f, 0.f};

        #pragma unroll 1
        for (int ks = 0; ks < 16; ++ks) {
            const short8 a0 = *(const short8*)&A_lds[((ks * 2 + 0) * 64 + l) * 8];
            const short8 a1 = *(const short8*)&A_lds[((ks * 2 + 1) * 64 + l) * 8];
            const short* wb_base = Wb + ((size_t)ks * 64 + l) * 8;
            #pragma unroll
            for (int gt = 0; gt < 4; ++gt) {
                #pragma unroll
                for (int uq = 0; uq < 4; ++uq) {
                    const int nt = gt * 16 + w * 4 + uq;
                    const short8 b = *(const short8*)(wb_base + (size_t)nt * 16 * 64 * 8);
                    acc[gt][0][uq] = __builtin_amdgcn_mfma_f32_16x16x32_bf16(a0, b, acc[gt][0][uq], 0, 0, 0);
                    acc[gt][1][uq] = __builtin_amdgcn_mfma_f32_16x16x32_bf16(a1, b, acc[gt][1][uq], 0, 0, 0);
                }
            }
        }

        // ---- fused LSTM pointwise (wave-local gates) ----
        #pragma unroll
        for (int mb = 0; mb < 2; ++mb) {
            #pragma unroll
            for (int uq = 0; uq < 4; ++uq) {
                const int u = w * 64 + uq * 16 + lc;
                const float bi = bias[u], bf = bias[256 + u], bg = bias[512 + u], bo = bias[768 + u];
                #pragma unroll
                for (int j = 0; j < 4; ++j) {
                    const int gr = row0 + mb * 16 + lr * 4 + j;
                    if (gr < nk) {
                        const int pos = rowlist[base + gr];
                        float cp = 0.0f;
                        if (kk > 0)           cp = c_buf[(size_t)(pos - B_DIM) * H_DIM + u];
                        else if (!done[pos])  cp = c0[(size_t)(pos & (B_DIM - 1)) * H_DIM + u];
                        const float si = sigm(acc[0][mb][uq][j] + bi);
                        const float sf = sigm(acc[1][mb][uq][j] + bf);
                        const float tg = tanh_fast(acc[2][mb][uq][j] + bg);
                        const float so = sigm(acc[3][mb][uq][j] + bo);
                        const float cn = sf * cp + si * tg;
                        const float hn = so * tanh_fast(cn);
                        c_buf[(size_t)pos * H_DIM + u] = cn;
                        out[(size_t)pos * H_DIM + u]  = hn;
                    }
                }
            }
        }
        __syncthreads();   // A_lds reuse
    }
}

// hT = out rows at t=511 ; cT = c_buf at t=511
__global__ __launch_bounds__(256) void k_final(const float* __restrict__ c_buf, float* __restrict__ out)
{
    const size_t i = (size_t)blockIdx.x * 256 + threadIdx.x;   // 0..65535
    const size_t featN = (size_t)T_DIM * B_DIM * H_DIM;
    const size_t last  = (size_t)(T_DIM - 1) * B_DIM * H_DIM;
    out[featN + i] = out[last + i];
    out[featN + (size_t)B_DIM * H_DIM + i] = c_buf[last + i];
}

extern "C" void kernel_launch(void* const* d_in, const int* in_sizes, int n_in,
                              void* d_out, int out_size, void* d_ws, size_t ws_size,
                              hipStream_t stream)
{
    const float* x    = (const float*)d_in[0];
    const float* h0   = (const float*)d_in[1];
    const float* c0   = (const float*)d_in[2];
    const float* W_ih = (const float*)d_in[3];
    const float* W_hh = (const float*)d_in[4];
    const float* b_ih = (const float*)d_in[5];
    const float* b_hh = (const float*)d_in[6];
    const int*   done = (const int*)d_in[7];
    float* out = (float*)d_out;

    char* ws = (char*)d_ws;
    size_t off = 0;
    float* c_buf = (float*)(ws + off);            off += (size_t)T_DIM * B_DIM * H_DIM * 4;  // 128 MiB
    unsigned int* Wb = (unsigned int*)(ws + off); off += (size_t)(K_DIM / 2) * G_DIM * 4;    // 1 MiB
    float* bias = (float*)(ws + off);             off += (size_t)G_DIM * 4;
    int* kmap    = (int*)(ws + off);              off += (size_t)T_DIM * B_DIM * 4;
    int* rowlist = (int*)(ws + off);              off += (size_t)T_DIM * B_DIM * 4;
    int* counts  = (int*)(ws + off);              off += 256;
    int* offs    = (int*)(ws + off);              off += 256;
    int* cursor  = (int*)(ws + off);              off += 256;

    k_prep_weights<<<1024, 256, 0, stream>>>(W_ih, W_hh, b_ih, b_hh, Wb, bias);
    k_prep_kmap<<<1, 256, 0, stream>>>(done, kmap, counts, offs, cursor);
    k_scatter<<<T_DIM * B_DIM / 256, 256, 0, stream>>>(kmap, offs, cursor, rowlist);

    int est = 70000;   // upper bound on round-0 rows; ~halves each round
    for (int k = 0; k < NROUNDS; ++k) {
        int grid = est / TILE_ROWS + 8;
        if (grid > 512) grid = 512;
        if (grid < 8) grid = 8;
        k_round<<<grid, 256, 0, stream>>>(x, h0, c0, done, (const short*)Wb, bias,
                                          counts, offs, rowlist, out, c_buf, k);
        est >>= 1;
    }
    k_final<<<B_DIM * H_DIM / 256, 256, 0, stream>>>(c_buf, out);
}

// Round 3
// 1186.109 us; speedup vs baseline: 3.6751x; 1.9296x over previous
//
#include <hip/hip_runtime.h>
#include <math.h>

#define T_DIM 512
#define B_DIM 256
#define D_DIM 256
#define H_DIM 256
#define G_DIM 1024   // 4*H
#define K_DIM 512    // D + H
#define NROUNDS 40
#define TILE_ROWS 32

typedef __attribute__((ext_vector_type(8))) short short8;
typedef __attribute__((ext_vector_type(4))) float f32x4;

__device__ __forceinline__ unsigned int f2bf(float f) {
    unsigned int b = __float_as_uint(f);
    return (b + 0x7FFFu + ((b >> 16) & 1u)) >> 16;   // round-to-nearest-even bf16
}
__device__ __forceinline__ float sigm(float x) { return 1.0f / (1.0f + __expf(-x)); }
__device__ __forceinline__ float tanh_fast(float x) { return 2.0f / (1.0f + __expf(-2.0f * x)) - 1.0f; }

// Prepack W into MFMA B-fragment order, bf16.
// Wb u32 slot idx: jp = idx&3, l = (idx>>2)&63, ks = (idx>>8)&15, nt = idx>>12
//   g = nt*16 + (l&15); k = ks*32 + ((l>>4)<<3) + 2*jp (+0,1)
//   W[k][g] = k<D ? W_ih[g][k] : W_hh[g][k-D]
__global__ __launch_bounds__(256) void k_prep_weights(
    const float* __restrict__ W_ih, const float* __restrict__ W_hh,
    const float* __restrict__ b_ih, const float* __restrict__ b_hh,
    unsigned int* __restrict__ Wb, float* __restrict__ bias)
{
    const int idx = blockIdx.x * 256 + threadIdx.x;   // 0 .. 262143
    const int jp = idx & 3, l = (idx >> 2) & 63, ks = (idx >> 8) & 15, nt = idx >> 12;
    const int g = nt * 16 + (l & 15);
    const int k0 = ks * 32 + ((l >> 4) << 3) + 2 * jp;   // even; k0,k0+1 same side of D boundary
    const float w0 = (k0 < D_DIM) ? W_ih[g * D_DIM + k0] : W_hh[g * H_DIM + (k0 - D_DIM)];
    const float w1 = (k0 + 1 < D_DIM) ? W_ih[g * D_DIM + k0 + 1] : W_hh[g * H_DIM + (k0 + 1 - D_DIM)];
    Wb[idx] = (f2bf(w1) << 16) | f2bf(w0);
    if (idx < G_DIM) bias[idx] = b_ih[idx] + b_hh[idx];
}

// Parallel kmap: thread per (t,b). k = t - max{t'<=t : done[t',b]==1}, else t.
// Block = one t-row (256 batch cols) -> backward scan is coalesced; expected ~2 steps.
// Also builds per-block histogram -> global counts.
__global__ __launch_bounds__(256) void k_kmap(
    const int* __restrict__ done, int* __restrict__ kmap, int* __restrict__ counts)
{
    __shared__ int lcnt[NROUNDS];
    const int tid = threadIdx.x;
    if (tid < NROUNDS) lcnt[tid] = 0;
    __syncthreads();
    const int t = blockIdx.x, b = tid;
    int kv = t;
    for (int tt = t; tt >= 0; --tt) {
        if (done[tt * B_DIM + b]) { kv = t - tt; break; }
    }
    if (kv > NROUNDS - 1) kv = NROUNDS - 1;   // safety clamp
    kmap[t * B_DIM + b] = kv;
    atomicAdd(&lcnt[kv], 1);
    __syncthreads();
    if (tid < NROUNDS && lcnt[tid] > 0) atomicAdd(&counts[tid], lcnt[tid]);
}

// offs = exclusive scan of counts; zero cursors. One tiny block.
__global__ __launch_bounds__(64) void k_offs(
    const int* __restrict__ counts, int* __restrict__ offs, int* __restrict__ cursor)
{
    if (threadIdx.x == 0) {
        int s = 0;
        for (int i = 0; i < NROUNDS; ++i) { offs[i] = s; s += counts[i]; }
    }
    if (threadIdx.x < NROUNDS) cursor[threadIdx.x] = 0;
}

// Two-level scatter: LDS local ranks + one global atomicAdd per (block, bin).
__global__ __launch_bounds__(256) void k_scatter(
    const int* __restrict__ kmap, const int* __restrict__ offs,
    int* __restrict__ cursor, int* __restrict__ rowlist)
{
    __shared__ int lcnt[NROUNDS];
    __shared__ int gbase[NROUNDS];
    const int tid = threadIdx.x;
    if (tid < NROUNDS) lcnt[tid] = 0;
    __syncthreads();
    const int pos = blockIdx.x * 256 + tid;
    const int kv = kmap[pos];
    const int lrank = atomicAdd(&lcnt[kv], 1);
    __syncthreads();
    if (tid < NROUNDS && lcnt[tid] > 0) gbase[tid] = atomicAdd(&cursor[tid], lcnt[tid]);
    __syncthreads();
    rowlist[offs[kv] + gbase[kv] + lrank] = pos;
}

// Round k: [nk x 512] x [512 x 1024] bf16 MFMA + fused LSTM pointwise.
// Block: 256 thr (4 waves). Wave w owns hidden units u in [w*64, w*64+64) -- all 4 gates.
// A staged in LDS in fragment order: slot ((ks*2+mb)*64 + l)*8 + j  <->
//   row = mb*16 + (l&15), k = ks*32 + ((l>>4)<<3) + j
__global__ __launch_bounds__(256, 2) void k_round(
    const float* __restrict__ x, const float* __restrict__ h0,
    const float* __restrict__ c0, const int* __restrict__ done,
    const short* __restrict__ Wb, const float* __restrict__ bias,
    const int* __restrict__ counts, const int* __restrict__ offs,
    const int* __restrict__ rowlist,
    float* __restrict__ out, float* __restrict__ c_buf, int kk)
{
    __shared__ short A_lds[16 * 2 * 64 * 8];   // 32 KiB
    __shared__ int posr[TILE_ROWS];
    const int nk = counts[kk];
    const int base = offs[kk];
    const int tid = threadIdx.x;
    const int w = tid >> 6, l = tid & 63;
    const int lr = l >> 4, lc = l & 15;

    // per-thread gate biases (wave-local hidden units) -- tile-invariant
    const int u_pw = w * 64 + lc;   // + uq*16 added below
    const float bi0 = bias[u_pw],        bi1 = bias[u_pw + 16],        bi2 = bias[u_pw + 32],        bi3 = bias[u_pw + 48];
    const float bf0 = bias[256 + u_pw],  bf1 = bias[256 + u_pw + 16],  bf2 = bias[256 + u_pw + 32],  bf3 = bias[256 + u_pw + 48];
    const float bg0 = bias[512 + u_pw],  bg1 = bias[512 + u_pw + 16],  bg2 = bias[512 + u_pw + 32],  bg3 = bias[512 + u_pw + 48];
    const float bo0 = bias[768 + u_pw],  bo1 = bias[768 + u_pw + 16],  bo2 = bias[768 + u_pw + 32],  bo3 = bias[768 + u_pw + 48];
    const float bI[4] = {bi0, bi1, bi2, bi3};
    const float bF[4] = {bf0, bf1, bf2, bf3};
    const float bG[4] = {bg0, bg1, bg2, bg3};
    const float bO[4] = {bo0, bo1, bo2, bo3};

    for (int tile = blockIdx.x; tile * TILE_ROWS < nk; tile += gridDim.x) {
        const int row0 = tile * TILE_ROWS;

        if (tid < TILE_ROWS)
            posr[tid] = (row0 + tid < nk) ? rowlist[base + row0 + tid] : -1;
        __syncthreads();

        // ---- stage A tile (f32 -> bf16, fragment order, conflict-free) ----
        unsigned int* A_u32 = (unsigned int*)A_lds;
        for (int it = 0; it < 32; ++it) {
            const int s = it * 256 + tid;             // 0..8191 u32 slots
            const int ks = s >> 9, mb = (s >> 8) & 1, sl = (s >> 2) & 63, jp = s & 3;
            const int r = mb * 16 + (sl & 15);
            const int c = ks * 32 + ((sl >> 4) << 3) + 2 * jp;
            const int pos = posr[r];
            float v0 = 0.0f, v1 = 0.0f;
            if (pos >= 0) {
                if (c < D_DIM) {
                    v0 = x[(size_t)pos * D_DIM + c];
                    v1 = x[(size_t)pos * D_DIM + c + 1];
                } else {
                    const int u = c - D_DIM;
                    if (kk > 0) {
                        const float* hp = out + (size_t)(pos - B_DIM) * H_DIM + u;
                        v0 = hp[0]; v1 = hp[1];
                    } else if (!done[pos]) {
                        const float* hp = h0 + (size_t)(pos & (B_DIM - 1)) * H_DIM + u;
                        v0 = hp[0]; v1 = hp[1];
                    }
                }
            }
            A_u32[s] = (f2bf(v1) << 16) | f2bf(v0);
        }
        __syncthreads();

        // ---- MFMA: acc[gt][mb][uq] ----
        f32x4 acc[4][2][4];
        #pragma unroll
        for (int gt = 0; gt < 4; ++gt)
            #pragma unroll
            for (int mb = 0; mb < 2; ++mb)
                #pragma unroll
                for (int uq = 0; uq < 4; ++uq)
                    acc[gt][mb][uq] = (f32x4){0.f, 0.f, 0.f, 0.f};

        #pragma unroll 1
        for (int ks = 0; ks < 16; ++ks) {
            const short8 a0 = *(const short8*)&A_lds[((ks * 2 + 0) * 64 + l) * 8];
            const short8 a1 = *(const short8*)&A_lds[((ks * 2 + 1) * 64 + l) * 8];
            const short* wb_base = Wb + ((size_t)ks * 64 + l) * 8;
            #pragma unroll
            for (int gt = 0; gt < 4; ++gt) {
                #pragma unroll
                for (int uq = 0; uq < 4; ++uq) {
                    const int nt = gt * 16 + w * 4 + uq;
                    const short8 b = *(const short8*)(wb_base + (size_t)nt * 16 * 64 * 8);
                    acc[gt][0][uq] = __builtin_amdgcn_mfma_f32_16x16x32_bf16(a0, b, acc[gt][0][uq], 0, 0, 0);
                    acc[gt][1][uq] = __builtin_amdgcn_mfma_f32_16x16x32_bf16(a1, b, acc[gt][1][uq], 0, 0, 0);
                }
            }
        }

        // ---- fused LSTM pointwise (wave-local gates) ----
        #pragma unroll
        for (int mb = 0; mb < 2; ++mb) {
            #pragma unroll
            for (int uq = 0; uq < 4; ++uq) {
                const int u = w * 64 + uq * 16 + lc;
                #pragma unroll
                for (int j = 0; j < 4; ++j) {
                    const int gr = row0 + mb * 16 + lr * 4 + j;
                    if (gr < nk) {
                        const int pos = posr[mb * 16 + lr * 4 + j];
                        float cp = 0.0f;
                        if (kk > 0)           cp = c_buf[(size_t)(pos - B_DIM) * H_DIM + u];
                        else if (!done[pos])  cp = c0[(size_t)(pos & (B_DIM - 1)) * H_DIM + u];
                        const float si = sigm(acc[0][mb][uq][j] + bI[uq]);
                        const float sf = sigm(acc[1][mb][uq][j] + bF[uq]);
                        const float tg = tanh_fast(acc[2][mb][uq][j] + bG[uq]);
                        const float so = sigm(acc[3][mb][uq][j] + bO[uq]);
                        const float cn = sf * cp + si * tg;
                        const float hn = so * tanh_fast(cn);
                        c_buf[(size_t)pos * H_DIM + u] = cn;
                        out[(size_t)pos * H_DIM + u]  = hn;
                    }
                }
            }
        }
        __syncthreads();   // A_lds / posr reuse
    }
}

// hT = out rows at t=511 ; cT = c_buf at t=511
__global__ __launch_bounds__(256) void k_final(const float* __restrict__ c_buf, float* __restrict__ out)
{
    const size_t i = (size_t)blockIdx.x * 256 + threadIdx.x;   // 0..65535
    const size_t featN = (size_t)T_DIM * B_DIM * H_DIM;
    const size_t last  = (size_t)(T_DIM - 1) * B_DIM * H_DIM;
    out[featN + i] = out[last + i];
    out[featN + (size_t)B_DIM * H_DIM + i] = c_buf[last + i];
}

// zero the counts array (40 ints)
__global__ __launch_bounds__(64) void k_zero(int* __restrict__ counts)
{
    if (threadIdx.x < NROUNDS) counts[threadIdx.x] = 0;
}

extern "C" void kernel_launch(void* const* d_in, const int* in_sizes, int n_in,
                              void* d_out, int out_size, void* d_ws, size_t ws_size,
                              hipStream_t stream)
{
    const float* x    = (const float*)d_in[0];
    const float* h0   = (const float*)d_in[1];
    const float* c0   = (const float*)d_in[2];
    const float* W_ih = (const float*)d_in[3];
    const float* W_hh = (const float*)d_in[4];
    const float* b_ih = (const float*)d_in[5];
    const float* b_hh = (const float*)d_in[6];
    const int*   done = (const int*)d_in[7];
    float* out = (float*)d_out;

    char* ws = (char*)d_ws;
    size_t off = 0;
    float* c_buf = (float*)(ws + off);            off += (size_t)T_DIM * B_DIM * H_DIM * 4;  // 128 MiB
    unsigned int* Wb = (unsigned int*)(ws + off); off += (size_t)(K_DIM / 2) * G_DIM * 4;    // 1 MiB
    float* bias = (float*)(ws + off);             off += (size_t)G_DIM * 4;
    int* kmap    = (int*)(ws + off);              off += (size_t)T_DIM * B_DIM * 4;
    int* rowlist = (int*)(ws + off);              off += (size_t)T_DIM * B_DIM * 4;
    int* counts  = (int*)(ws + off);              off += 256;
    int* offs    = (int*)(ws + off);              off += 256;
    int* cursor  = (int*)(ws + off);              off += 256;

    k_zero<<<1, 64, 0, stream>>>(counts);
    k_prep_weights<<<1024, 256, 0, stream>>>(W_ih, W_hh, b_ih, b_hh, Wb, bias);
    k_kmap<<<T_DIM, 256, 0, stream>>>(done, kmap, counts);
    k_offs<<<1, 64, 0, stream>>>(counts, offs, cursor);
    k_scatter<<<T_DIM * B_DIM / 256, 256, 0, stream>>>(kmap, offs, cursor, rowlist);

    int est = 70000;   // upper bound on round-0 rows; ~halves each round
    for (int k = 0; k < NROUNDS; ++k) {
        int grid = est / TILE_ROWS + 8;
        if (grid > 512) grid = 512;
        if (grid < 8) grid = 8;
        k_round<<<grid, 256, 0, stream>>>(x, h0, c0, done, (const short*)Wb, bias,
                                          counts, offs, rowlist, out, c_buf, k);
        est >>= 1;
    }
    k_final<<<B_DIM * H_DIM / 256, 256, 0, stream>>>(c_buf, out);
}